// Round 23
// baseline (286.541 us; speedup 1.0000x reference)
//
#include <hip/hip_runtime.h>

#define NN 20000
#define NE 640000
#define Cc 128
#define C2 256
#define BN_EPS 1e-5f

typedef __attribute__((ext_vector_type(8))) short bf16x8;
typedef __attribute__((ext_vector_type(4))) float f32x4;

// ---- workspace layout (float offsets) ----
#define WS_P     0                      // ushort[NN*Cc] bf16 P (first half of slot)
#define WS_XBF   (NN*Cc/2)              // ushort[NN*Cc] bf16 x (second half of P slot)
#define WS_Q     (NN*Cc)                // ushort[NN*Cc] bf16 Q
#define WS_CNTT  (2*NN*Cc)              // [NN] float
#define WS_CNTS  (2*NN*Cc + NN)         // [NN] int
#define WS_STATS (2*NN*Cc + 2*NN)       // [768]
#define WS_W1BF  (WS_STATS + 768)       // ushort[2*128*128] folded W1 bf16 [half][o][c]
#define WS_B1P   (WS_W1BF + C2*Cc)      // [128]
#define WS_W2BF  (WS_B1P + Cc)          // ushort[128*128] folded W2 bf16 [o][c]
#define WS_B2P   (WS_W2BF + Cc*Cc)      // [128]
#define WS_ROWPTR (WS_B2P + 128)        // int[NN+1] CSR row pointers for tgt

// z (bf16) for edge e lives in the FIRST 256 B of out-row e's 512 B slot.
// nbr (bf16) lives at the start of d_out until k_pq consumes it.

static __device__ inline unsigned short f2bf(float f) {
  union { float f; unsigned u; } v; v.f = f;
  unsigned r = v.u + 0x7fffu + ((v.u >> 16) & 1u);
  return (unsigned short)(r >> 16);
}
static __device__ inline float bf2f(unsigned short h) {
  union { unsigned u; float f; } v; v.u = (unsigned)h << 16; return v.f;
}

// merged: zero stats/cntS + cast x->bf16 + CSR rowptr build from sorted tgt.
// grid = NN*Cc/2048 = 1250 blocks x 256 threads = 320000 threads.
__global__ __launch_bounds__(256) void k_prep(const float* __restrict__ x,
                                              unsigned short* __restrict__ xbf,
                                              float* __restrict__ stats,
                                              int* __restrict__ cntS,
                                              const int* __restrict__ tgt,
                                              int* __restrict__ rowptr) {
  int g = blockIdx.x * 256 + threadIdx.x;
  if (g < 768) stats[g] = 0.0f;
  if (g < NN) cntS[g] = 0;
  // cast 8 elems
  int i = g * 8;
  float4 v0 = *(const float4*)&x[i];
  float4 v1 = *(const float4*)&x[i + 4];
  bf16x8 o;
  o[0] = (short)f2bf(v0.x); o[1] = (short)f2bf(v0.y);
  o[2] = (short)f2bf(v0.z); o[3] = (short)f2bf(v0.w);
  o[4] = (short)f2bf(v1.x); o[5] = (short)f2bf(v1.y);
  o[6] = (short)f2bf(v1.z); o[7] = (short)f2bf(v1.w);
  *(bf16x8*)&xbf[i] = o;
  // rowptr boundary-detect: 2 edges per thread (640000 / 320000)
  #pragma unroll
  for (int k = 0; k < 2; ++k) {
    int e = g + k * 320000;
    int t1 = tgt[e];
    int t0 = (e == 0) ? -1 : tgt[e - 1];
    for (int n = t0 + 1; n <= t1; ++n) rowptr[n] = e;
    if (e == NE - 1) {
      for (int n = t1 + 1; n <= NN; ++n) rowptr[n] = NE;
    }
  }
}

// one block (128 threads) per node: segment sum of bf16 x + fused src-histogram.
// Edge range from precomputed rowptr (no per-block binary search).
__global__ void k_nbr(const unsigned short* __restrict__ xbf, const int* __restrict__ rowptr,
                      const int* __restrict__ src, unsigned short* __restrict__ nbr,
                      float* __restrict__ cntT, int* __restrict__ cntS) {
  int node = blockIdx.x;
  int lo = rowptr[node];
  int hi = rowptr[node + 1];
  int c = threadIdx.x;
  for (int e = lo + c; e < hi; e += 128) atomicAdd(&cntS[src[e]], 1);
  float a0 = 0.f, a1 = 0.f, a2 = 0.f, a3 = 0.f;
  int e = lo;
  for (; e + 7 < hi; e += 8) {
    int s0 = src[e],     s1 = src[e + 1], s2 = src[e + 2], s3 = src[e + 3];
    int s4 = src[e + 4], s5 = src[e + 5], s6 = src[e + 6], s7 = src[e + 7];
    float v0 = bf2f(xbf[(size_t)s0 * Cc + c]), v1 = bf2f(xbf[(size_t)s1 * Cc + c]);
    float v2 = bf2f(xbf[(size_t)s2 * Cc + c]), v3 = bf2f(xbf[(size_t)s3 * Cc + c]);
    float v4 = bf2f(xbf[(size_t)s4 * Cc + c]), v5 = bf2f(xbf[(size_t)s5 * Cc + c]);
    float v6 = bf2f(xbf[(size_t)s6 * Cc + c]), v7 = bf2f(xbf[(size_t)s7 * Cc + c]);
    a0 += v0 + v4; a1 += v1 + v5; a2 += v2 + v6; a3 += v3 + v7;
  }
  for (; e < hi; ++e) a0 += bf2f(xbf[(size_t)src[e] * Cc + c]);
  nbr[(size_t)node * Cc + c] = f2bf((a0 + a1) + (a2 + a3));
  if (c == 0) cntT[node] = (float)(hi - lo);
}

// BN1 stats from bf16 tables. 512 blocks x 512 threads.
__global__ __launch_bounds__(512) void k_stats1(const unsigned short* __restrict__ nbr,
                                                const unsigned short* __restrict__ xbf,
                                                const float* __restrict__ cntT,
                                                const int* __restrict__ cntS,
                                                float* __restrict__ stats) {
  __shared__ float ls[3][4][Cc];
  int c = threadIdx.x & 127;
  int y = threadIdx.x >> 7;
  float sa = 0.f, qa = 0.f, sb = 0.f, qb = 0.f;
  for (int t = blockIdx.x + y * 512; t < NN; t += 2048) {
    float ct = cntT[t];
    float cs = (float)cntS[t];
    float v1 = bf2f(nbr[(size_t)t * Cc + c]);
    float v2 = bf2f(xbf[(size_t)t * Cc + c]);
    sa += ct * v1; qa += ct * v1 * v1;
    sb += cs * v2; qb += cs * v2 * v2;
  }
  if (y) {
    ls[y - 1][0][c] = sa; ls[y - 1][1][c] = qa;
    ls[y - 1][2][c] = sb; ls[y - 1][3][c] = qb;
  }
  __syncthreads();
  if (!y) {
    #pragma unroll
    for (int j = 0; j < 3; ++j) {
      sa += ls[j][0][c]; qa += ls[j][1][c];
      sb += ls[j][2][c]; qb += ls[j][3][c];
    }
    atomicAdd(&stats[c], sa);
    atomicAdd(&stats[256 + c], qa);
    atomicAdd(&stats[128 + c], sb);
    atomicAdd(&stats[256 + 128 + c], qb);
  }
}

// fold BN1 into W1 -> bf16 [half][o][c] + fp32 b1p
__global__ void k_fold1(const float* __restrict__ W1, const float* __restrict__ b1,
                        const float* __restrict__ g1, const float* __restrict__ be1,
                        const float* __restrict__ stats,
                        unsigned short* __restrict__ W1bf, float* __restrict__ b1p) {
  __shared__ float red[C2];
  int o = blockIdx.x, c = threadIdx.x;
  const float inv = 1.0f / (float)NE;
  float mu = stats[c] * inv;
  float var = stats[256 + c] * inv - mu * mu;
  float a = g1[c] * rsqrtf(var + BN_EPS);
  float cc = be1[c] - mu * a;
  float w = W1[o * C2 + c];
  W1bf[(size_t)(c >> 7) * Cc * Cc + o * Cc + (c & 127)] = f2bf(w * a);
  red[c] = w * cc;
  __syncthreads();
  for (int s = 128; s > 0; s >>= 1) { if (c < s) red[c] += red[c + s]; __syncthreads(); }
  if (c == 0) b1p[o] = b1[o] + red[0];
}

// P = nbr@W1a'.T ; Q = x@W1b'.T  via bf16 MFMA (swapped ops), tail-guarded.
#define WPAD 136
__global__ __launch_bounds__(256) void k_pq(const unsigned short* __restrict__ nbr,
                                            const unsigned short* __restrict__ xbf,
                                            const unsigned short* __restrict__ W1bf,
                                            unsigned short* __restrict__ P,
                                            unsigned short* __restrict__ Q) {
  __shared__ unsigned short Wl[128 * WPAD];
  const int half = blockIdx.y;
  const unsigned short* __restrict__ A = half ? xbf : nbr;
  unsigned short* __restrict__ Out = half ? Q : P;
  const unsigned short* __restrict__ Wt = W1bf + (size_t)half * Cc * Cc;
  int tid = threadIdx.x;
  int n0 = blockIdx.x * 64;

  for (int i = tid; i < 2048; i += 256) {
    int row = i >> 4, col = (i & 15) * 8;
    *(bf16x8*)&Wl[row * WPAD + col] = *(const bf16x8*)&Wt[row * Cc + col];
  }

  int w = tid >> 6, l = tid & 63;
  int la = l & 15, kb = l >> 4;
  int node = n0 + w * 16 + la;
  int ld = node < NN ? node : NN - 1;

  bf16x8 zfr[4];
  #pragma unroll
  for (int kk = 0; kk < 4; ++kk)
    zfr[kk] = *(const bf16x8*)&A[(size_t)ld * Cc + kk * 32 + kb * 8];
  __syncthreads();

  f32x4 acc[8];
  #pragma unroll
  for (int n = 0; n < 8; ++n) acc[n] = (f32x4){0.f, 0.f, 0.f, 0.f};

  #pragma unroll
  for (int kk = 0; kk < 4; ++kk) {
    #pragma unroll
    for (int n = 0; n < 8; ++n) {
      bf16x8 wa = *(const bf16x8*)&Wl[(n * 16 + la) * WPAD + kk * 32 + kb * 8];
      acc[n] = __builtin_amdgcn_mfma_f32_16x16x32_bf16(wa, zfr[kk], acc[n], 0, 0, 0);
    }
  }

  if (node < NN) {
    #pragma unroll
    for (int n = 0; n < 8; ++n) {
      int o0 = n * 16 + kb * 4;
      ushort4 v;
      v.x = f2bf(acc[n][0]); v.y = f2bf(acc[n][1]);
      v.z = f2bf(acc[n][2]); v.w = f2bf(acc[n][3]);
      *(ushort4*)&Out[(size_t)node * Cc + o0] = v;
    }
  }
}

// BN2 stats + z materialization; bf16 P/Q gathers, XCD-bijective swizzle.
__global__ __launch_bounds__(512) void k_stats2(const unsigned short* __restrict__ P,
                                                const unsigned short* __restrict__ Q,
                                                const float* __restrict__ b1p,
                                                const int* __restrict__ tgt,
                                                const int* __restrict__ src,
                                                float* __restrict__ stats,
                                                unsigned short* __restrict__ zout) {
  __shared__ float s2[7][Cc], q2[7][Cc];
  const int nwg = NE / 512;
  const int q8 = nwg >> 3, r8 = nwg & 7;
  int orig = blockIdx.x;
  int xcd = orig & 7, idx = orig >> 3;
  int bid = (xcd < r8 ? xcd * (q8 + 1) : r8 * (q8 + 1) + (xcd - r8) * q8) + idx;
  int cp = threadIdx.x & 63;
  int y = threadIdx.x >> 6;
  int c0 = cp * 2;
  int e0 = bid * 512;
  float2 b = *(const float2*)&b1p[c0];
  float s0 = 0.f, s1 = 0.f, q0 = 0.f, q1 = 0.f;
  for (int e = e0 + y * 8; e < e0 + 512; e += 64) {
    int t[8], sr[8];
    #pragma unroll
    for (int j = 0; j < 8; ++j) { t[j] = tgt[e + j]; sr[j] = src[e + j]; }
    ushort2 pv[8], qv[8];
    #pragma unroll
    for (int j = 0; j < 8; ++j) pv[j] = *(const ushort2*)&P[(size_t)t[j] * Cc + c0];
    #pragma unroll
    for (int j = 0; j < 8; ++j) qv[j] = *(const ushort2*)&Q[(size_t)sr[j] * Cc + c0];
    #pragma unroll
    for (int j = 0; j < 8; ++j) {
      float z0 = fmaxf(bf2f(pv[j].x) + bf2f(qv[j].x) + b.x, 0.f);
      float z1 = fmaxf(bf2f(pv[j].y) + bf2f(qv[j].y) + b.y, 0.f);
      ushort2 zz; zz.x = f2bf(z0); zz.y = f2bf(z1);
      *(ushort2*)&zout[(size_t)(e + j) * 256 + c0] = zz;
      s0 += z0; s1 += z1; q0 += z0 * z0; q1 += z1 * z1;
    }
  }
  if (y) { s2[y - 1][c0] = s0; s2[y - 1][c0 + 1] = s1;
           q2[y - 1][c0] = q0; q2[y - 1][c0 + 1] = q1; }
  __syncthreads();
  if (!y) {
    #pragma unroll
    for (int j = 0; j < 7; ++j) {
      s0 += s2[j][c0]; s1 += s2[j][c0 + 1];
      q0 += q2[j][c0]; q1 += q2[j][c0 + 1];
    }
    atomicAdd(&stats[512 + c0], s0);
    atomicAdd(&stats[512 + c0 + 1], s1);
    atomicAdd(&stats[640 + c0], q0);
    atomicAdd(&stats[640 + c0 + 1], q1);
  }
}

// fold BN2 into W2, emit bf16 [o][c] weights + fp32 bias
__global__ void k_fold2(const float* __restrict__ W2, const float* __restrict__ b2,
                        const float* __restrict__ g2, const float* __restrict__ be2,
                        const float* __restrict__ stats,
                        unsigned short* __restrict__ W2bf, float* __restrict__ b2p) {
  __shared__ float red[Cc];
  int o = blockIdx.x, c = threadIdx.x;
  const float inv = 1.0f / (float)NE;
  float mu = stats[512 + c] * inv;
  float var = stats[640 + c] * inv - mu * mu;
  float a = g2[c] * rsqrtf(var + BN_EPS);
  float cc = be2[c] - mu * a;
  float w = W2[o * Cc + c];
  W2bf[o * Cc + c] = f2bf(w * a);
  red[c] = w * cc;
  __syncthreads();
  for (int s = 64; s > 0; s >>= 1) { if (c < s) red[c] += red[c + s]; __syncthreads(); }
  if (c == 0) b2p[o] = b2[o] + red[0];
}

// out[e][o] = relu( z[e]@W2' + b2' ): streaming bf16 MFMA GEMM, operand-swapped.
// z loads NON-TEMPORAL (read-once-then-dead); out stores NON-TEMPORAL
// (never re-read) -> neither stream pollutes L2/L3.
__global__ __launch_bounds__(256) void k_out_mfma(const unsigned short* __restrict__ zin,
                                                  const unsigned short* __restrict__ W2bf,
                                                  const float* __restrict__ b2p,
                                                  float* __restrict__ out) {
  __shared__ unsigned short Wl[128 * WPAD];
  int tid = threadIdx.x;
  int e0 = blockIdx.x * 64;

  for (int i = tid; i < 2048; i += 256) {
    int row = i >> 4, col = (i & 15) * 8;
    *(bf16x8*)&Wl[row * WPAD + col] = *(const bf16x8*)&W2bf[row * Cc + col];
  }

  int w = tid >> 6, l = tid & 63;
  int la = l & 15, kb = l >> 4;
  int e = e0 + w * 16 + la;

  bf16x8 zfr[4];
  #pragma unroll
  for (int kk = 0; kk < 4; ++kk)
    zfr[kk] = __builtin_nontemporal_load((const bf16x8*)&zin[(size_t)e * 256 + kk * 32 + kb * 8]);
  __syncthreads();

  f32x4 acc[8];
  #pragma unroll
  for (int n = 0; n < 8; ++n) acc[n] = (f32x4){0.f, 0.f, 0.f, 0.f};

  #pragma unroll
  for (int kk = 0; kk < 4; ++kk) {
    #pragma unroll
    for (int n = 0; n < 8; ++n) {
      bf16x8 wa = *(const bf16x8*)&Wl[(n * 16 + la) * WPAD + kk * 32 + kb * 8];
      acc[n] = __builtin_amdgcn_mfma_f32_16x16x32_bf16(wa, zfr[kk], acc[n], 0, 0, 0);
    }
  }

  #pragma unroll
  for (int n = 0; n < 8; ++n) {
    int o0 = n * 16 + kb * 4;
    float4 bb = *(const float4*)&b2p[o0];
    f32x4 v;
    v[0] = fmaxf(acc[n][0] + bb.x, 0.f);
    v[1] = fmaxf(acc[n][1] + bb.y, 0.f);
    v[2] = fmaxf(acc[n][2] + bb.z, 0.f);
    v[3] = fmaxf(acc[n][3] + bb.w, 0.f);
    __builtin_nontemporal_store(v, (f32x4*)&out[(size_t)e * Cc + o0]);
  }
}

extern "C" void kernel_launch(void* const* d_in, const int* in_sizes, int n_in,
                              void* d_out, int out_size, void* d_ws, size_t ws_size,
                              hipStream_t stream) {
  (void)in_sizes; (void)n_in; (void)out_size; (void)ws_size;
  const float* x   = (const float*)d_in[0];
  const float* g1  = (const float*)d_in[1];
  const float* be1 = (const float*)d_in[2];
  const float* W1  = (const float*)d_in[3];
  const float* b1  = (const float*)d_in[4];
  const float* g2  = (const float*)d_in[5];
  const float* be2 = (const float*)d_in[6];
  const float* W2  = (const float*)d_in[7];
  const float* b2  = (const float*)d_in[8];
  const int* tgt   = (const int*)d_in[9];
  const int* src   = (const int*)d_in[10];

  float* ws  = (float*)d_ws;
  float* out = (float*)d_out;

  unsigned short* P    = (unsigned short*)(ws + WS_P);
  unsigned short* xbf  = (unsigned short*)(ws + WS_XBF);
  unsigned short* Q    = (unsigned short*)(ws + WS_Q);
  float* cntT  = ws + WS_CNTT;
  int*   cntS  = (int*)(ws + WS_CNTS);
  float* stats = ws + WS_STATS;
  unsigned short* W1bf = (unsigned short*)(ws + WS_W1BF);
  float* b1p   = ws + WS_B1P;
  unsigned short* W2bf = (unsigned short*)(ws + WS_W2BF);
  float* b2p   = ws + WS_B2P;
  int*   rowptr = (int*)(ws + WS_ROWPTR);
  unsigned short* nbr  = (unsigned short*)out;  // bf16 scratch; consumed before z overwrites

  k_prep  <<<dim3(NN * Cc / 2048),   dim3(256), 0, stream>>>(x, xbf, stats, cntS, tgt, rowptr);
  k_nbr   <<<dim3(NN),              dim3(Cc),  0, stream>>>(xbf, rowptr, src, nbr, cntT, cntS);
  k_stats1<<<dim3(512),             dim3(512), 0, stream>>>(nbr, xbf, cntT, cntS, stats);
  k_fold1 <<<dim3(Cc),              dim3(C2),  0, stream>>>(W1, b1, g1, be1, stats, W1bf, b1p);
  k_pq    <<<dim3((NN + 63) / 64, 2), dim3(256), 0, stream>>>(nbr, xbf, W1bf, P, Q);
  k_stats2<<<dim3(NE / 512),        dim3(512), 0, stream>>>(P, Q, b1p, tgt, src, stats,
                                                            (unsigned short*)out);
  k_fold2 <<<dim3(Cc),              dim3(Cc),  0, stream>>>(W2, b2, g2, be2, stats, W2bf, b2p);
  k_out_mfma<<<dim3(NE / 64),       dim3(256), 0, stream>>>((const unsigned short*)out,
                                                            W2bf, b2p, out);
}

// Round 26
// 244.597 us; speedup vs baseline: 1.1715x; 1.1715x over previous
//
#include <hip/hip_runtime.h>

#define NN 20000
#define NE 640000
#define Cc 128
#define C2 256
#define BN_EPS 1e-5f

typedef __attribute__((ext_vector_type(8))) short bf16x8;
typedef __attribute__((ext_vector_type(4))) float f32x4;

// ---- workspace layout (float offsets) ----
#define WS_P     0                      // ushort[NN*Cc] bf16 P (first half of slot)
#define WS_XBF   (NN*Cc/2)              // ushort[NN*Cc] bf16 x (second half of P slot)
#define WS_Q     (NN*Cc)                // ushort[NN*Cc] bf16 Q
#define WS_CNTT  (2*NN*Cc)              // [NN] float
#define WS_CNTS  (2*NN*Cc + NN)         // [NN] int
#define WS_STATS (2*NN*Cc + 2*NN)       // [768]
#define WS_W1BF  (WS_STATS + 768)       // ushort[2*128*128] folded W1 bf16 [half][o][c]
#define WS_B1P   (WS_W1BF + C2*Cc)      // [128]
#define WS_W2BF  (WS_B1P + Cc)          // ushort[128*128] folded W2 bf16 [o][c]
#define WS_B2P   (WS_W2BF + Cc*Cc)      // [128]
#define WS_ROWPTR (WS_B2P + 128)        // int[NN+1] CSR row pointers for tgt

// z (bf16) for edge e lives in the FIRST 256 B of out-row e's 512 B slot.
// nbr (bf16) lives at the start of d_out until k_pq consumes it.

static __device__ inline unsigned short f2bf(float f) {
  union { float f; unsigned u; } v; v.f = f;
  unsigned r = v.u + 0x7fffu + ((v.u >> 16) & 1u);
  return (unsigned short)(r >> 16);
}
static __device__ inline float bf2f(unsigned short h) {
  union { unsigned u; float f; } v; v.u = (unsigned)h << 16; return v.f;
}

// merged: zero stats/cntS + cast x->bf16 + CSR rowptr build from sorted tgt.
__global__ __launch_bounds__(256) void k_prep(const float* __restrict__ x,
                                              unsigned short* __restrict__ xbf,
                                              float* __restrict__ stats,
                                              int* __restrict__ cntS,
                                              const int* __restrict__ tgt,
                                              int* __restrict__ rowptr) {
  int g = blockIdx.x * 256 + threadIdx.x;
  if (g < 768) stats[g] = 0.0f;
  if (g < NN) cntS[g] = 0;
  int i = g * 8;
  float4 v0 = *(const float4*)&x[i];
  float4 v1 = *(const float4*)&x[i + 4];
  bf16x8 o;
  o[0] = (short)f2bf(v0.x); o[1] = (short)f2bf(v0.y);
  o[2] = (short)f2bf(v0.z); o[3] = (short)f2bf(v0.w);
  o[4] = (short)f2bf(v1.x); o[5] = (short)f2bf(v1.y);
  o[6] = (short)f2bf(v1.z); o[7] = (short)f2bf(v1.w);
  *(bf16x8*)&xbf[i] = o;
  #pragma unroll
  for (int k = 0; k < 2; ++k) {
    int e = g + k * 320000;
    int t1 = tgt[e];
    int t0 = (e == 0) ? -1 : tgt[e - 1];
    for (int n = t0 + 1; n <= t1; ++n) rowptr[n] = e;
    if (e == NE - 1) {
      for (int n = t1 + 1; n <= NN; ++n) rowptr[n] = NE;
    }
  }
}

// one block (128 threads) per node: segment sum of bf16 x + fused src-histogram.
__global__ void k_nbr(const unsigned short* __restrict__ xbf, const int* __restrict__ rowptr,
                      const int* __restrict__ src, unsigned short* __restrict__ nbr,
                      float* __restrict__ cntT, int* __restrict__ cntS) {
  int node = blockIdx.x;
  int lo = rowptr[node];
  int hi = rowptr[node + 1];
  int c = threadIdx.x;
  for (int e = lo + c; e < hi; e += 128) atomicAdd(&cntS[src[e]], 1);
  float a0 = 0.f, a1 = 0.f, a2 = 0.f, a3 = 0.f;
  int e = lo;
  for (; e + 7 < hi; e += 8) {
    int s0 = src[e],     s1 = src[e + 1], s2 = src[e + 2], s3 = src[e + 3];
    int s4 = src[e + 4], s5 = src[e + 5], s6 = src[e + 6], s7 = src[e + 7];
    float v0 = bf2f(xbf[(size_t)s0 * Cc + c]), v1 = bf2f(xbf[(size_t)s1 * Cc + c]);
    float v2 = bf2f(xbf[(size_t)s2 * Cc + c]), v3 = bf2f(xbf[(size_t)s3 * Cc + c]);
    float v4 = bf2f(xbf[(size_t)s4 * Cc + c]), v5 = bf2f(xbf[(size_t)s5 * Cc + c]);
    float v6 = bf2f(xbf[(size_t)s6 * Cc + c]), v7 = bf2f(xbf[(size_t)s7 * Cc + c]);
    a0 += v0 + v4; a1 += v1 + v5; a2 += v2 + v6; a3 += v3 + v7;
  }
  for (; e < hi; ++e) a0 += bf2f(xbf[(size_t)src[e] * Cc + c]);
  nbr[(size_t)node * Cc + c] = f2bf((a0 + a1) + (a2 + a3));
  if (c == 0) cntT[node] = (float)(hi - lo);
}

// BN1 stats from bf16 tables. 512 blocks x 512 threads.
__global__ __launch_bounds__(512) void k_stats1(const unsigned short* __restrict__ nbr,
                                                const unsigned short* __restrict__ xbf,
                                                const float* __restrict__ cntT,
                                                const int* __restrict__ cntS,
                                                float* __restrict__ stats) {
  __shared__ float ls[3][4][Cc];
  int c = threadIdx.x & 127;
  int y = threadIdx.x >> 7;
  float sa = 0.f, qa = 0.f, sb = 0.f, qb = 0.f;
  for (int t = blockIdx.x + y * 512; t < NN; t += 2048) {
    float ct = cntT[t];
    float cs = (float)cntS[t];
    float v1 = bf2f(nbr[(size_t)t * Cc + c]);
    float v2 = bf2f(xbf[(size_t)t * Cc + c]);
    sa += ct * v1; qa += ct * v1 * v1;
    sb += cs * v2; qb += cs * v2 * v2;
  }
  if (y) {
    ls[y - 1][0][c] = sa; ls[y - 1][1][c] = qa;
    ls[y - 1][2][c] = sb; ls[y - 1][3][c] = qb;
  }
  __syncthreads();
  if (!y) {
    #pragma unroll
    for (int j = 0; j < 3; ++j) {
      sa += ls[j][0][c]; qa += ls[j][1][c];
      sb += ls[j][2][c]; qb += ls[j][3][c];
    }
    atomicAdd(&stats[c], sa);
    atomicAdd(&stats[256 + c], qa);
    atomicAdd(&stats[128 + c], sb);
    atomicAdd(&stats[256 + 128 + c], qb);
  }
}

// fold BN1 into W1 -> bf16 [half][o][c] + fp32 b1p
__global__ void k_fold1(const float* __restrict__ W1, const float* __restrict__ b1,
                        const float* __restrict__ g1, const float* __restrict__ be1,
                        const float* __restrict__ stats,
                        unsigned short* __restrict__ W1bf, float* __restrict__ b1p) {
  __shared__ float red[C2];
  int o = blockIdx.x, c = threadIdx.x;
  const float inv = 1.0f / (float)NE;
  float mu = stats[c] * inv;
  float var = stats[256 + c] * inv - mu * mu;
  float a = g1[c] * rsqrtf(var + BN_EPS);
  float cc = be1[c] - mu * a;
  float w = W1[o * C2 + c];
  W1bf[(size_t)(c >> 7) * Cc * Cc + o * Cc + (c & 127)] = f2bf(w * a);
  red[c] = w * cc;
  __syncthreads();
  for (int s = 128; s > 0; s >>= 1) { if (c < s) red[c] += red[c + s]; __syncthreads(); }
  if (c == 0) b1p[o] = b1[o] + red[0];
}

// P = nbr@W1a'.T ; Q = x@W1b'.T  via bf16 MFMA (swapped ops), tail-guarded.
#define WPAD 136
__global__ __launch_bounds__(256) void k_pq(const unsigned short* __restrict__ nbr,
                                            const unsigned short* __restrict__ xbf,
                                            const unsigned short* __restrict__ W1bf,
                                            unsigned short* __restrict__ P,
                                            unsigned short* __restrict__ Q) {
  __shared__ unsigned short Wl[128 * WPAD];
  const int half = blockIdx.y;
  const unsigned short* __restrict__ A = half ? xbf : nbr;
  unsigned short* __restrict__ Out = half ? Q : P;
  const unsigned short* __restrict__ Wt = W1bf + (size_t)half * Cc * Cc;
  int tid = threadIdx.x;
  int n0 = blockIdx.x * 64;

  for (int i = tid; i < 2048; i += 256) {
    int row = i >> 4, col = (i & 15) * 8;
    *(bf16x8*)&Wl[row * WPAD + col] = *(const bf16x8*)&Wt[row * Cc + col];
  }

  int w = tid >> 6, l = tid & 63;
  int la = l & 15, kb = l >> 4;
  int node = n0 + w * 16 + la;
  int ld = node < NN ? node : NN - 1;

  bf16x8 zfr[4];
  #pragma unroll
  for (int kk = 0; kk < 4; ++kk)
    zfr[kk] = *(const bf16x8*)&A[(size_t)ld * Cc + kk * 32 + kb * 8];
  __syncthreads();

  f32x4 acc[8];
  #pragma unroll
  for (int n = 0; n < 8; ++n) acc[n] = (f32x4){0.f, 0.f, 0.f, 0.f};

  #pragma unroll
  for (int kk = 0; kk < 4; ++kk) {
    #pragma unroll
    for (int n = 0; n < 8; ++n) {
      bf16x8 wa = *(const bf16x8*)&Wl[(n * 16 + la) * WPAD + kk * 32 + kb * 8];
      acc[n] = __builtin_amdgcn_mfma_f32_16x16x32_bf16(wa, zfr[kk], acc[n], 0, 0, 0);
    }
  }

  if (node < NN) {
    #pragma unroll
    for (int n = 0; n < 8; ++n) {
      int o0 = n * 16 + kb * 4;
      ushort4 v;
      v.x = f2bf(acc[n][0]); v.y = f2bf(acc[n][1]);
      v.z = f2bf(acc[n][2]); v.w = f2bf(acc[n][3]);
      *(ushort4*)&Out[(size_t)node * Cc + o0] = v;
    }
  }
}

// BN2 stats + z materialization; bf16 P/Q gathers, XCD-bijective swizzle.
__global__ __launch_bounds__(512) void k_stats2(const unsigned short* __restrict__ P,
                                                const unsigned short* __restrict__ Q,
                                                const float* __restrict__ b1p,
                                                const int* __restrict__ tgt,
                                                const int* __restrict__ src,
                                                float* __restrict__ stats,
                                                unsigned short* __restrict__ zout) {
  __shared__ float s2[7][Cc], q2[7][Cc];
  const int nwg = NE / 512;
  const int q8 = nwg >> 3, r8 = nwg & 7;
  int orig = blockIdx.x;
  int xcd = orig & 7, idx = orig >> 3;
  int bid = (xcd < r8 ? xcd * (q8 + 1) : r8 * (q8 + 1) + (xcd - r8) * q8) + idx;
  int cp = threadIdx.x & 63;
  int y = threadIdx.x >> 6;
  int c0 = cp * 2;
  int e0 = bid * 512;
  float2 b = *(const float2*)&b1p[c0];
  float s0 = 0.f, s1 = 0.f, q0 = 0.f, q1 = 0.f;
  for (int e = e0 + y * 8; e < e0 + 512; e += 64) {
    int t[8], sr[8];
    #pragma unroll
    for (int j = 0; j < 8; ++j) { t[j] = tgt[e + j]; sr[j] = src[e + j]; }
    ushort2 pv[8], qv[8];
    #pragma unroll
    for (int j = 0; j < 8; ++j) pv[j] = *(const ushort2*)&P[(size_t)t[j] * Cc + c0];
    #pragma unroll
    for (int j = 0; j < 8; ++j) qv[j] = *(const ushort2*)&Q[(size_t)sr[j] * Cc + c0];
    #pragma unroll
    for (int j = 0; j < 8; ++j) {
      float z0 = fmaxf(bf2f(pv[j].x) + bf2f(qv[j].x) + b.x, 0.f);
      float z1 = fmaxf(bf2f(pv[j].y) + bf2f(qv[j].y) + b.y, 0.f);
      ushort2 zz; zz.x = f2bf(z0); zz.y = f2bf(z1);
      *(ushort2*)&zout[(size_t)(e + j) * 256 + c0] = zz;
      s0 += z0; s1 += z1; q0 += z0 * z0; q1 += z1 * z1;
    }
  }
  if (y) { s2[y - 1][c0] = s0; s2[y - 1][c0 + 1] = s1;
           q2[y - 1][c0] = q0; q2[y - 1][c0 + 1] = q1; }
  __syncthreads();
  if (!y) {
    #pragma unroll
    for (int j = 0; j < 7; ++j) {
      s0 += s2[j][c0]; s1 += s2[j][c0 + 1];
      q0 += q2[j][c0]; q1 += q2[j][c0 + 1];
    }
    atomicAdd(&stats[512 + c0], s0);
    atomicAdd(&stats[512 + c0 + 1], s1);
    atomicAdd(&stats[640 + c0], q0);
    atomicAdd(&stats[640 + c0 + 1], q1);
  }
}

// fold BN2 into W2, emit bf16 [o][c] weights + fp32 bias
__global__ void k_fold2(const float* __restrict__ W2, const float* __restrict__ b2,
                        const float* __restrict__ g2, const float* __restrict__ be2,
                        const float* __restrict__ stats,
                        unsigned short* __restrict__ W2bf, float* __restrict__ b2p) {
  __shared__ float red[Cc];
  int o = blockIdx.x, c = threadIdx.x;
  const float inv = 1.0f / (float)NE;
  float mu = stats[512 + c] * inv;
  float var = stats[640 + c] * inv - mu * mu;
  float a = g2[c] * rsqrtf(var + BN_EPS);
  float cc = be2[c] - mu * a;
  float w = W2[o * Cc + c];
  W2bf[o * Cc + c] = f2bf(w * a);
  red[c] = w * cc;
  __syncthreads();
  for (int s = 64; s > 0; s >>= 1) { if (c < s) red[c] += red[c + s]; __syncthreads(); }
  if (c == 0) b2p[o] = b2[o] + red[0];
}

// out[e][o] = relu( z[e]@W2' + b2' ): streaming bf16 MFMA GEMM, operand-swapped.
// z loads CACHED (just written by k_stats2 -> L2/L3-warm; NT loads regressed
// +15us in round 23 by skipping the warm hierarchy). Out stores NT (dead stream).
__global__ __launch_bounds__(256) void k_out_mfma(const unsigned short* __restrict__ zin,
                                                  const unsigned short* __restrict__ W2bf,
                                                  const float* __restrict__ b2p,
                                                  float* __restrict__ out) {
  __shared__ unsigned short Wl[128 * WPAD];
  int tid = threadIdx.x;
  int e0 = blockIdx.x * 64;

  for (int i = tid; i < 2048; i += 256) {
    int row = i >> 4, col = (i & 15) * 8;
    *(bf16x8*)&Wl[row * WPAD + col] = *(const bf16x8*)&W2bf[row * Cc + col];
  }

  int w = tid >> 6, l = tid & 63;
  int la = l & 15, kb = l >> 4;
  int e = e0 + w * 16 + la;

  bf16x8 zfr[4];
  #pragma unroll
  for (int kk = 0; kk < 4; ++kk)
    zfr[kk] = *(const bf16x8*)&zin[(size_t)e * 256 + kk * 32 + kb * 8];
  __syncthreads();

  f32x4 acc[8];
  #pragma unroll
  for (int n = 0; n < 8; ++n) acc[n] = (f32x4){0.f, 0.f, 0.f, 0.f};

  #pragma unroll
  for (int kk = 0; kk < 4; ++kk) {
    #pragma unroll
    for (int n = 0; n < 8; ++n) {
      bf16x8 wa = *(const bf16x8*)&Wl[(n * 16 + la) * WPAD + kk * 32 + kb * 8];
      acc[n] = __builtin_amdgcn_mfma_f32_16x16x32_bf16(wa, zfr[kk], acc[n], 0, 0, 0);
    }
  }

  #pragma unroll
  for (int n = 0; n < 8; ++n) {
    int o0 = n * 16 + kb * 4;
    float4 bb = *(const float4*)&b2p[o0];
    f32x4 v;
    v[0] = fmaxf(acc[n][0] + bb.x, 0.f);
    v[1] = fmaxf(acc[n][1] + bb.y, 0.f);
    v[2] = fmaxf(acc[n][2] + bb.z, 0.f);
    v[3] = fmaxf(acc[n][3] + bb.w, 0.f);
    __builtin_nontemporal_store(v, (f32x4*)&out[(size_t)e * Cc + o0]);
  }
}

extern "C" void kernel_launch(void* const* d_in, const int* in_sizes, int n_in,
                              void* d_out, int out_size, void* d_ws, size_t ws_size,
                              hipStream_t stream) {
  (void)in_sizes; (void)n_in; (void)out_size; (void)ws_size;
  const float* x   = (const float*)d_in[0];
  const float* g1  = (const float*)d_in[1];
  const float* be1 = (const float*)d_in[2];
  const float* W1  = (const float*)d_in[3];
  const float* b1  = (const float*)d_in[4];
  const float* g2  = (const float*)d_in[5];
  const float* be2 = (const float*)d_in[6];
  const float* W2  = (const float*)d_in[7];
  const float* b2  = (const float*)d_in[8];
  const int* tgt   = (const int*)d_in[9];
  const int* src   = (const int*)d_in[10];

  float* ws  = (float*)d_ws;
  float* out = (float*)d_out;

  unsigned short* P    = (unsigned short*)(ws + WS_P);
  unsigned short* xbf  = (unsigned short*)(ws + WS_XBF);
  unsigned short* Q    = (unsigned short*)(ws + WS_Q);
  float* cntT  = ws + WS_CNTT;
  int*   cntS  = (int*)(ws + WS_CNTS);
  float* stats = ws + WS_STATS;
  unsigned short* W1bf = (unsigned short*)(ws + WS_W1BF);
  float* b1p   = ws + WS_B1P;
  unsigned short* W2bf = (unsigned short*)(ws + WS_W2BF);
  float* b2p   = ws + WS_B2P;
  int*   rowptr = (int*)(ws + WS_ROWPTR);
  unsigned short* nbr  = (unsigned short*)out;  // bf16 scratch; consumed before z overwrites

  k_prep  <<<dim3(NN * Cc / 2048),   dim3(256), 0, stream>>>(x, xbf, stats, cntS, tgt, rowptr);
  k_nbr   <<<dim3(NN),              dim3(Cc),  0, stream>>>(xbf, rowptr, src, nbr, cntT, cntS);
  k_stats1<<<dim3(512),             dim3(512), 0, stream>>>(nbr, xbf, cntT, cntS, stats);
  k_fold1 <<<dim3(Cc),              dim3(C2),  0, stream>>>(W1, b1, g1, be1, stats, W1bf, b1p);
  k_pq    <<<dim3((NN + 63) / 64, 2), dim3(256), 0, stream>>>(nbr, xbf, W1bf, P, Q);
  k_stats2<<<dim3(NE / 512),        dim3(512), 0, stream>>>(P, Q, b1p, tgt, src, stats,
                                                            (unsigned short*)out);
  k_fold2 <<<dim3(Cc),              dim3(Cc),  0, stream>>>(W2, b2, g2, be2, stats, W2bf, b2p);
  k_out_mfma<<<dim3(NE / 64),       dim3(256), 0, stream>>>((const unsigned short*)out,
                                                            W2bf, b2p, out);
}